// Round 15
// baseline (169.902 us; speedup 1.0000x reference)
//
#include <hip/hip_runtime.h>
#include <hip/hip_bf16.h>

#define NT 1536
#define SCALE 0.17677669529663687f  // (256/8)^-0.5

typedef __attribute__((ext_vector_type(8))) short bf16x8;
typedef __attribute__((ext_vector_type(4))) float f32x4;

static __device__ __forceinline__ unsigned short f2b(float x) {
    __hip_bfloat16 h = __float2bfloat16(x);
    union { __hip_bfloat16 b; unsigned short u; } cv; cv.b = h; return cv.u;
}
static __device__ __forceinline__ float b2f(unsigned short u) {
    union { float f; unsigned v; } c; c.v = ((unsigned)u) << 16; return c.f;
}

// ------ prep: bf16 conversions + W transposes -------------------------------
__global__ __launch_bounds__(256) void prep(
    const float* __restrict__ x_cls, const float* __restrict__ x_reg,
    const float* __restrict__ W_cls, const float* __restrict__ W_reg,
    unsigned short* __restrict__ xb_c, unsigned short* __restrict__ xb_r,
    unsigned short* __restrict__ Wt_c, unsigned short* __restrict__ Wt_r)
{
    const int u = blockIdx.x * 256 + threadIdx.x;   // 700416 total
    if (u < 393216) {
        xb_c[u] = f2b(x_cls[u]);
    } else if (u < 491520) {
        const int v = u - 393216;
        xb_r[v] = f2b(x_reg[v]);
    } else if (u < 688128) {
        const int v = u - 491520;                   // Wt_c[j*256+k] = W_cls[k*768+j]
        const int j = v >> 8, k = v & 255;
        Wt_c[v] = f2b(W_cls[k * 768 + j]);
    } else if (u < 700416) {
        const int v = u - 688128;                   // Wt_r[j*64+k] = W_reg[k*192+j]
        const int j = v >> 6, k = v & 63;
        Wt_r[v] = f2b(W_reg[k * 192 + j]);
    }
}

// ------ MFMA projection GEMM + fused per-head L2 normalize (2-deep prefetch) -
__global__ __launch_bounds__(256) void gemm_mfma(
    const unsigned short* __restrict__ xb_c, const unsigned short* __restrict__ Wt_c,
    const unsigned short* __restrict__ xb_r, const unsigned short* __restrict__ Wt_r,
    float* __restrict__ qkv_c, unsigned short* __restrict__ qb_c,
    float* __restrict__ qkv_r, unsigned short* __restrict__ qb_r)
{
    const unsigned short *A, *B;
    float* qkv; unsigned short* qb;
    int K, NN, KS;
    const bool isreg = (blockIdx.z == 1);
    if (!isreg) { A = xb_c; B = Wt_c; qkv = qkv_c; qb = qb_c; K = 256; NN = 768; KS = 8; }
    else { if (blockIdx.x >= 3) return;
           A = xb_r; B = Wt_r; qkv = qkv_r; qb = qb_r; K = 64;  NN = 192; KS = 2; }
    __shared__ short Ai[64 * 40], Bj[64 * 40];
    const int t = threadIdx.x, lane = t & 63;
    const int wv = t >> 6, wr = wv >> 1, wc = wv & 1;
    const int i0 = blockIdx.y * 64, j0 = blockIdx.x * 64;
    const int srow = t >> 2, sc8 = (t & 3) * 8;
    f32x4 acc[2][2];
    #pragma unroll
    for (int a = 0; a < 2; a++)
        #pragma unroll
        for (int b = 0; b < 2; b++) acc[a][b] = (f32x4){0, 0, 0, 0};
    float4 ra = *(const float4*)&A[(i0 + srow) * K + 0 * 32 + sc8];
    float4 rb = *(const float4*)&B[(j0 + srow) * K + 0 * 32 + sc8];
    float4 ra2, rb2;
    if (KS > 1) {
        ra2 = *(const float4*)&A[(i0 + srow) * K + 1 * 32 + sc8];
        rb2 = *(const float4*)&B[(j0 + srow) * K + 1 * 32 + sc8];
    }
    for (int ks = 0; ks < KS; ks++) {
        __syncthreads();
        *(float4*)&Ai[srow * 40 + sc8] = ra;
        *(float4*)&Bj[srow * 40 + sc8] = rb;
        ra = ra2; rb = rb2;
        if (ks + 2 < KS) {
            ra2 = *(const float4*)&A[(i0 + srow) * K + (ks + 2) * 32 + sc8];
            rb2 = *(const float4*)&B[(j0 + srow) * K + (ks + 2) * 32 + sc8];
        }
        __syncthreads();
        const int k8 = (lane >> 4) * 8;
        bf16x8 af[2], bf_[2];
        #pragma unroll
        for (int fr = 0; fr < 2; fr++)
            af[fr] = *(const bf16x8*)&Ai[(wr * 32 + fr * 16 + (lane & 15)) * 40 + k8];
        #pragma unroll
        for (int fc = 0; fc < 2; fc++)
            bf_[fc] = *(const bf16x8*)&Bj[(wc * 32 + fc * 16 + (lane & 15)) * 40 + k8];
        #pragma unroll
        for (int fr = 0; fr < 2; fr++)
            #pragma unroll
            for (int fc = 0; fc < 2; fc++)
                acc[fr][fc] = __builtin_amdgcn_mfma_f32_16x16x32_bf16(af[fr], bf_[fc], acc[fr][fc], 0, 0, 0);
    }
    #pragma unroll
    for (int fr = 0; fr < 2; fr++)
        #pragma unroll
        for (int r4 = 0; r4 < 4; r4++) {
            const int i = i0 + wr * 32 + fr * 16 + (lane >> 4) * 4 + r4;
            if (!isreg) {
                float s = acc[fr][0][r4] * acc[fr][0][r4] + acc[fr][1][r4] * acc[fr][1][r4];
                s += __shfl_xor(s, 1); s += __shfl_xor(s, 2);
                s += __shfl_xor(s, 4); s += __shfl_xor(s, 8);
                const float inv = 1.0f / sqrtf(s);
                #pragma unroll
                for (int fc = 0; fc < 2; fc++) {
                    const int j = j0 + wc * 32 + fc * 16 + (lane & 15);
                    const float v = acc[fr][fc][r4];
                    qkv[i * NN + j] = v;
                    qb[i * NN + j] = f2b(v * inv);
                }
            } else {
                #pragma unroll
                for (int fc = 0; fc < 2; fc++) {
                    const float v = acc[fr][fc][r4];
                    float s = v * v;
                    s += __shfl_xor(s, 1); s += __shfl_xor(s, 2); s += __shfl_xor(s, 4);
                    const float inv = 1.0f / sqrtf(s);
                    const int j = j0 + wc * 32 + fc * 16 + (lane & 15);
                    qkv[i * NN + j] = v;
                    qb[i * NN + j] = f2b(v * inv);
                }
            }
        }
}

// ------ sim/obj bit matrices (2-deep prefetch, grid 576) --------------------
__global__ __launch_bounds__(256) void bits_mfma(
    const unsigned short* __restrict__ qb_cls, const unsigned short* __restrict__ qb_reg,
    const float* __restrict__ cls_score, const float* __restrict__ fg_score,
    unsigned* __restrict__ simbits, unsigned* __restrict__ objbits)
{
    __shared__ short Ai[64 * 40], Bj[64 * 40];
    __shared__ float csi[64], csj[64], fgi[64], fgj[64];
    __shared__ unsigned simw[64][2], objw[64][2];
    const int t = threadIdx.x;
    const int lane = t & 63;
    const int wv = t >> 6, wr = wv >> 1, wc = wv & 1;
    const int sr = t >> 2, sc = t & 3;
    const int iB = blockIdx.x / 24, jB = blockIdx.x % 24;
    const int i0 = iB * 64, j0 = jB * 64;
    if (t < 64)       { csi[t] = cls_score[i0 + t]; fgi[t] = fg_score[i0 + t]; }
    else if (t < 128) { csj[t - 64] = cls_score[j0 + t - 64]; fgj[t - 64] = fg_score[j0 + t - 64]; }
    f32x4 ac[2][2], ar[2][2];
    #pragma unroll
    for (int a = 0; a < 2; a++)
        #pragma unroll
        for (int b = 0; b < 2; b++) { ac[a][b] = (f32x4){0,0,0,0}; ar[a][b] = (f32x4){0,0,0,0}; }
    #define LD_A(s) ((s) < 8 ? *(const float4*)&qb_cls[(i0 + sr) * 768 + 512 + (s) * 32 + sc * 8] \
                             : *(const float4*)&qb_reg[(i0 + sr) * 192 + 128 + ((s) - 8) * 32 + sc * 8])
    #define LD_B(s) ((s) < 8 ? *(const float4*)&qb_cls[(j0 + sr) * 768 + 512 + (s) * 32 + sc * 8] \
                             : *(const float4*)&qb_reg[(j0 + sr) * 192 + 128 + ((s) - 8) * 32 + sc * 8])
    float4 ra = LD_A(0), rb = LD_B(0);
    float4 ra2 = LD_A(1), rb2 = LD_B(1);
    for (int ks = 0; ks < 10; ks++) {
        __syncthreads();
        *(float4*)&Ai[sr * 40 + sc * 8] = ra;
        *(float4*)&Bj[sr * 40 + sc * 8] = rb;
        ra = ra2; rb = rb2;
        if (ks + 2 < 10) { ra2 = LD_A(ks + 2); rb2 = LD_B(ks + 2); }
        __syncthreads();
        const int k8 = (lane >> 4) * 8;
        bf16x8 af[2], bf_[2];
        #pragma unroll
        for (int fr = 0; fr < 2; fr++)
            af[fr] = *(const bf16x8*)&Ai[(wr * 32 + fr * 16 + (lane & 15)) * 40 + k8];
        #pragma unroll
        for (int fc = 0; fc < 2; fc++)
            bf_[fc] = *(const bf16x8*)&Bj[(wc * 32 + fc * 16 + (lane & 15)) * 40 + k8];
        if (ks < 8) {
            #pragma unroll
            for (int fr = 0; fr < 2; fr++)
                #pragma unroll
                for (int fc = 0; fc < 2; fc++)
                    ac[fr][fc] = __builtin_amdgcn_mfma_f32_16x16x32_bf16(af[fr], bf_[fc], ac[fr][fc], 0, 0, 0);
        } else {
            #pragma unroll
            for (int fr = 0; fr < 2; fr++)
                #pragma unroll
                for (int fc = 0; fc < 2; fc++)
                    ar[fr][fc] = __builtin_amdgcn_mfma_f32_16x16x32_bf16(af[fr], bf_[fc], ar[fr][fc], 0, 0, 0);
        }
    }
    #undef LD_A
    #undef LD_B
    #pragma unroll
    for (int fr = 0; fr < 2; fr++)
        #pragma unroll
        for (int r4 = 0; r4 < 4; r4++) {
            const int rloc = wr * 32 + fr * 16 + (lane >> 4) * 4 + r4;
            const float ci = csi[rloc] - 0.1f, fgv = fgi[rloc] - 0.1f;
            unsigned sm[2], om[2];
            #pragma unroll
            for (int fc = 0; fc < 2; fc++) {
                const int cloc = wc * 32 + fc * 16 + (lane & 15);
                const bool clsb = csj[cloc] > ci;
                const bool fgb  = fgj[cloc] > fgv;
                const bool sim = (ac[fr][fc][r4] * 0.125f > 0.75f) && clsb && fgb;
                const bool obj = sim && (ar[fr][fc][r4] * 0.125f > 0.75f);
                unsigned long long bs = __ballot(sim);
                unsigned long long bo = __ballot(obj);
                const int g = lane >> 4;
                sm[fc] = (unsigned)((bs >> (16 * g)) & 0xFFFFull);
                om[fc] = (unsigned)((bo >> (16 * g)) & 0xFFFFull);
            }
            if ((lane & 15) == 0) {
                simw[rloc][wc] = sm[0] | (sm[1] << 16);
                objw[rloc][wc] = om[0] | (om[1] << 16);
            }
        }
    __syncthreads();
    if (t < 128) {
        const int row = t >> 1, w = t & 1;
        simbits[(i0 + row) * 48 + jB * 2 + w] = simw[row][w];
        objbits[(i0 + row) * 48 + jB * 2 + w] = objw[row][w];
    }
}

// ------ denom ∥ expand, STRIPE-INTERLEAVED roles (grid 4688) ----------------
// bid%8==7 -> denom tile bid/8 (0..585, active <576); else expand chunk
// (bid/8)*7 + bid%8 (0..4101, active <4096). Both roles co-resident from t=0.
__global__ __launch_bounds__(256) void denomexpand(
    const unsigned short* __restrict__ qb_cls, const unsigned short* __restrict__ qb_reg,
    const float* __restrict__ cls_score,
    const unsigned* __restrict__ simbits, const unsigned* __restrict__ objbits,
    float* __restrict__ Dcpart, float* __restrict__ Drpart,
    float* __restrict__ sim_out, float* __restrict__ obj_out)
{
    __shared__ short Ai[64 * 40], Bj[64 * 40];
    __shared__ short Kr[64 * 72], Qr[64 * 72];
    __shared__ float csi[64], csj[64];
    __shared__ unsigned bw[6][48];
    __shared__ float invs[6];
    const int t = threadIdx.x;
    const int bid = blockIdx.x;
    if ((bid & 7) == 7) {
        // ================= denom role =================
        const int didx = bid >> 3;
        if (didx >= 576) return;
        const int iB = didx / 24, jB = didx % 24;
        const int i0 = iB * 64, j0 = jB * 64;
        const int lane = t & 63;
        const int wv = t >> 6, wr = wv >> 1, wc = wv & 1;
        const int sr = t >> 2, sc = t & 3;
        if (t < 64)       csj[t] = cls_score[j0 + t];
        else if (t < 128) csi[t - 64] = cls_score[i0 + t - 64];
        #pragma unroll
        for (int it = 0; it < 2; it++) {
            const int u = it * 256 + t;
            const int r = u >> 3, c = u & 7;
            *(float4*)&Kr[r * 72 + c * 8] = *(const float4*)&qb_reg[(j0 + r) * 192 + 64 + c * 8];
            *(float4*)&Qr[r * 72 + c * 8] = *(const float4*)&qb_reg[(i0 + r) * 192 + 0 + c * 8];
        }
        __syncthreads();
        float cI[2], cJ[8];
        #pragma unroll
        for (int fc = 0; fc < 2; fc++) cI[fc] = csi[wc * 32 + fc * 16 + (lane & 15)] - 0.1f;
        #pragma unroll
        for (int fr = 0; fr < 2; fr++)
            #pragma unroll
            for (int r4 = 0; r4 < 4; r4++)
                cJ[fr * 4 + r4] = csj[wr * 32 + fr * 16 + (lane >> 4) * 4 + r4];
        float pC[2][8], pR[2][8];
        const bool g0 = (lane >> 4) == 0;
        const bf16x8 zz = {0, 0, 0, 0, 0, 0, 0, 0};
        float4 ra = *(const float4*)&qb_cls[(j0 + sr) * 768 + 256 + 0 * 32 + sc * 8];
        float4 rb = *(const float4*)&qb_cls[(i0 + sr) * 768 + 0   + 0 * 32 + sc * 8];
        float4 ra2 = *(const float4*)&qb_cls[(j0 + sr) * 768 + 256 + 1 * 32 + sc * 8];
        float4 rb2 = *(const float4*)&qb_cls[(i0 + sr) * 768 + 0   + 1 * 32 + sc * 8];
        for (int h = 0; h < 8; h++) {
            __syncthreads();
            *(float4*)&Ai[sr * 40 + sc * 8] = ra;
            *(float4*)&Bj[sr * 40 + sc * 8] = rb;
            ra = ra2; rb = rb2;
            if (h + 2 < 8) {
                ra2 = *(const float4*)&qb_cls[(j0 + sr) * 768 + 256 + (h + 2) * 32 + sc * 8];
                rb2 = *(const float4*)&qb_cls[(i0 + sr) * 768 + 0   + (h + 2) * 32 + sc * 8];
            }
            __syncthreads();
            const int k8 = (lane >> 4) * 8;
            bf16x8 a[2], b[2], arg[2], brg[2];
            #pragma unroll
            for (int fr = 0; fr < 2; fr++) {
                const int row = wr * 32 + fr * 16 + (lane & 15);
                a[fr] = *(const bf16x8*)&Ai[row * 40 + k8];
                arg[fr] = g0 ? *(const bf16x8*)&Kr[row * 72 + h * 8] : zz;
            }
            #pragma unroll
            for (int fc = 0; fc < 2; fc++) {
                const int row = wc * 32 + fc * 16 + (lane & 15);
                b[fc] = *(const bf16x8*)&Bj[row * 40 + k8];
                brg[fc] = g0 ? *(const bf16x8*)&Qr[row * 72 + h * 8] : zz;
            }
            f32x4 acc[2][2], racc[2][2];
            #pragma unroll
            for (int fr = 0; fr < 2; fr++)
                #pragma unroll
                for (int fc = 0; fc < 2; fc++) {
                    acc[fr][fc] = (f32x4){0,0,0,0};
                    racc[fr][fc] = (f32x4){0,0,0,0};
                    acc[fr][fc] = __builtin_amdgcn_mfma_f32_16x16x32_bf16(a[fr], b[fc], acc[fr][fc], 0, 0, 0);
                    racc[fr][fc] = __builtin_amdgcn_mfma_f32_16x16x32_bf16(arg[fr], brg[fc], racc[fr][fc], 0, 0, 0);
                }
            #pragma unroll
            for (int fc = 0; fc < 2; fc++) {
                float sC = 0.f, sR = 0.f;
                #pragma unroll
                for (int fr = 0; fr < 2; fr++)
                    #pragma unroll
                    for (int r4 = 0; r4 < 4; r4++) {
                        const float cj = cJ[fr * 4 + r4];
                        const float lc = (cj > cI[fc]) ? acc[fr][fc][r4] * SCALE * cj : 0.0f;
                        sC += __expf(lc);
                        sR += __expf(racc[fr][fc][r4] * SCALE);
                    }
                pC[fc][h] = sC; pR[fc][h] = sR;
            }
        }
        #pragma unroll
        for (int fc = 0; fc < 2; fc++)
            #pragma unroll
            for (int h = 0; h < 8; h++) {
                float v = pC[fc][h]; v += __shfl_xor(v, 16); v += __shfl_xor(v, 32);
                float u = pR[fc][h]; u += __shfl_xor(u, 16); u += __shfl_xor(u, 32);
                if (lane < 16) {
                    const int i = i0 + wc * 32 + fc * 16 + lane;
                    const int p = jB * 2 + wr;
                    Dcpart[(p * NT + i) * 8 + h] = v;
                    Drpart[(p * NT + i) * 8 + h] = u;
                }
            }
    } else {
        // ================= expand role =================
        const int eidx = (bid >> 3) * 7 + (bid & 7);
        if (eidx >= 4096) return;
        const int arr = eidx >> 11;             // 0: sim, 1: obj
        const int rem = eidx & 2047;
        const int copy = rem >> 8;              // 0..7
        const int blk = rem & 255;
        const int r0 = blk * 6;
        const unsigned* src = arr ? objbits : simbits;
        for (int u = t; u < 288; u += 256) bw[u / 48][u % 48] = src[(r0 + u / 48) * 48 + (u % 48)];
        __syncthreads();
        if (t < 6) {
            int c = 0;
            #pragma unroll 8
            for (int w = 0; w < 48; w++) c += __popc(bw[t][w]);
            invs[t] = 1.0f / (float)c;
        }
        __syncthreads();
        f32x4* dst = (f32x4*)((arr ? obj_out : sim_out)
                              + (size_t)copy * NT * NT + (size_t)r0 * NT);
        #pragma unroll
        for (int rpt = 0; rpt < 9; rpt++) {
            const int u = rpt * 256 + t;        // 0..2303; dst[u] is linear
            const int row = u / 384;
            const int c4 = u - row * 384;
            const int j0 = c4 * 4;
            const unsigned w = bw[row][j0 >> 5] >> (j0 & 31);
            const float on = arr ? invs[row] : 1.0f;
            f32x4 v;
            v.x = (w & 1u) ? on : 0.f;
            v.y = (w & 2u) ? on : 0.f;
            v.z = (w & 4u) ? on : 0.f;
            v.w = (w & 8u) ? on : 0.f;
            __builtin_nontemporal_store(v, dst + u);
        }
    }
}

// ------ sparse attn-out: one wave per row -----------------------------------
__global__ __launch_bounds__(256) void out_small(
    const float* __restrict__ qkv_cls, const unsigned short* __restrict__ qb_cls,
    const float* __restrict__ qkv_reg, const unsigned short* __restrict__ qb_reg,
    const float* __restrict__ cls_score,
    const unsigned* __restrict__ objbits,
    const float* __restrict__ Dcpart, const float* __restrict__ Drpart,
    const float* __restrict__ x_cls, const float* __restrict__ x_reg,
    float* __restrict__ out_cls, float* __restrict__ out_reg)
{
    const int i = (blockIdx.x << 2) + (threadIdx.x >> 6);
    const int l = threadIdx.x & 63;
    const int g = l >> 3;
    const ushort4 qu = *(const ushort4*)&qb_cls[i * 768 + 4 * l];
    const float qx = b2f(qu.x), qy = b2f(qu.y), qz = b2f(qu.z), qw = b2f(qu.w);
    const float qr = b2f(qb_reg[i * 192 + l]);
    unsigned myw = (l < 48) ? objbits[i * 48 + l] : 0u;
    int cnt = __popc(myw);
    #pragma unroll
    for (int m = 1; m < 64; m <<= 1) cnt += __shfl_xor(cnt, m);
    const int s = l & 7;
    float Dcv = 0.f, Drv = 0.f;
    #pragma unroll
    for (int p6 = 0; p6 < 6; p6++) {
        const int p = s * 6 + p6;
        Dcv += Dcpart[(p * NT + i) * 8 + g];
        Drv += Drpart[(p * NT + i) * 8 + g];
    }
    Dcv += __shfl_xor(Dcv, 1); Dcv += __shfl_xor(Dcv, 2); Dcv += __shfl_xor(Dcv, 4);
    Drv += __shfl_xor(Drv, 1); Drv += __shfl_xor(Drv, 2); Drv += __shfl_xor(Drv, 4);
    float a1x = 0.f, a1y = 0.f, a1z = 0.f, a1w = 0.f;
    float a2x = 0.f, a2y = 0.f, a2z = 0.f, a2w = 0.f;
    float rr1 = 0.f, rr2 = 0.f;
    for (int w = 0; w < 48; w++) {
        unsigned bits = __shfl(myw, w);
        while (bits) {
            const int b = __ffs(bits) - 1;
            bits &= bits - 1u;
            const int j = w * 32 + b;
            const ushort4 ku = *(const ushort4*)&qb_cls[j * 768 + 256 + 4 * l];
            const float4 v4 = *(const float4*)&qkv_cls[j * 768 + 512 + 4 * l];
            const float kr = b2f(qb_reg[j * 192 + 64 + l]);
            const float vr = qkv_reg[j * 192 + 128 + l];
            float dc = qx * b2f(ku.x) + qy * b2f(ku.y) + qz * b2f(ku.z) + qw * b2f(ku.w);
            dc += __shfl_xor(dc, 1); dc += __shfl_xor(dc, 2); dc += __shfl_xor(dc, 4);
            float dr = qr * kr;
            dr += __shfl_xor(dr, 1); dr += __shfl_xor(dr, 2); dr += __shfl_xor(dr, 4);
            const float cj = cls_score[j];
            const float ec = __expf(dc * SCALE * cj);   // obj => cls_mask==1
            const float er = __expf(dr * SCALE);
            a1x += ec * v4.x; a1y += ec * v4.y; a1z += ec * v4.z; a1w += ec * v4.w;
            a2x += er * v4.x; a2y += er * v4.y; a2z += er * v4.z; a2w += er * v4.w;
            rr1 += ec * vr;   rr2 += er * vr;
        }
    }
    const float iDc = 1.0f / Dcv, iDr = 1.0f / Drv;
    const float hi = 0.5f / (float)cnt;
    float4 o;
    o.x = (a1x * iDc + a2x * iDr) * hi;
    o.y = (a1y * iDc + a2y * iDr) * hi;
    o.z = (a1z * iDc + a2z * iDr) * hi;
    o.w = (a1w * iDc + a2w * iDr) * hi;
    *(float4*)&out_cls[i * 512 + 4 * l] = o;
    out_reg[i * 128 + l] = (rr1 * iDc + rr2 * iDr) * hi;
    *(float4*)&out_cls[i * 512 + 256 + 4 * l] = *(const float4*)&x_cls[i * 256 + 4 * l];
    out_reg[i * 128 + 64 + l] = x_reg[i * 64 + l];
}

extern "C" void kernel_launch(void* const* d_in, const int* in_sizes, int n_in,
                              void* d_out, int out_size, void* d_ws, size_t ws_size,
                              hipStream_t stream)
{
    (void)in_sizes; (void)n_in; (void)out_size; (void)ws_size;
    const float* x_cls     = (const float*)d_in[0];
    const float* x_reg     = (const float*)d_in[1];
    const float* cls_score = (const float*)d_in[2];
    const float* fg_score  = (const float*)d_in[3];
    const float* W_cls     = (const float*)d_in[4];
    const float* W_reg     = (const float*)d_in[5];

    float* out = (float*)d_out;
    float* out_cls = out;                  // 786432 floats
    float* out_reg = out + 786432;         // 196608 floats
    float* sim_out = out + 983040;         // 18874368 floats
    float* obj_out = out + 19857408;       // 18874368 floats

    // Scratch in d_ws (~15.6 MB)
    float* wsf = (float*)d_ws;
    float* qkv_cls = wsf;                               // 1,179,648 f
    float* qkv_reg = wsf + 1179648;                     //   294,912 f
    float* Dcpart  = wsf + 1474560;                     //   589,824 f
    float* Drpart  = wsf + 2064384;                     //   589,824 f
    unsigned short* qb_cls = (unsigned short*)(wsf + 2654208);  // 1,179,648 u16
    unsigned short* qb_reg = (unsigned short*)(wsf + 3244032);  //   294,912 u16
    unsigned short* xb_c   = (unsigned short*)(wsf + 3391488);  //   393,216 u16
    unsigned short* xb_r   = (unsigned short*)(wsf + 3588096);  //    98,304 u16
    unsigned short* Wt_c   = (unsigned short*)(wsf + 3637248);  //   196,608 u16
    unsigned short* Wt_r   = (unsigned short*)(wsf + 3735552);  //    12,288 u16
    unsigned* simbits = (unsigned*)(wsf + 3741696);     //    73,728 u32
    unsigned* objbits = simbits + 73728;                //    73,728 u32

    prep<<<2736, 256, 0, stream>>>(x_cls, x_reg, W_cls, W_reg, xb_c, xb_r, Wt_c, Wt_r);
    gemm_mfma<<<dim3(12, 24, 2), 256, 0, stream>>>(
        xb_c, Wt_c, xb_r, Wt_r, qkv_cls, qb_cls, qkv_reg, qb_reg);
    bits_mfma<<<576, 256, 0, stream>>>(
        qb_cls, qb_reg, cls_score, fg_score, simbits, objbits);
    denomexpand<<<4688, 256, 0, stream>>>(
        qb_cls, qb_reg, cls_score, simbits, objbits,
        Dcpart, Drpart, sim_out, obj_out);
    out_small<<<384, 256, 0, stream>>>(
        qkv_cls, qb_cls, qkv_reg, qb_reg, cls_score,
        objbits, Dcpart, Drpart, x_cls, x_reg, out_cls, out_reg);
}

// Round 16
// 68.379 us; speedup vs baseline: 2.4847x; 2.4847x over previous
//
#include <hip/hip_runtime.h>
#include <hip/hip_bf16.h>

#define NT 1536
#define SCALE 0.17677669529663687f  // (256/8)^-0.5

typedef __attribute__((ext_vector_type(8))) short bf16x8;
typedef __attribute__((ext_vector_type(4))) float f32x4;

static __device__ __forceinline__ unsigned short f2b(float x) {
    __hip_bfloat16 h = __float2bfloat16(x);
    union { __hip_bfloat16 b; unsigned short u; } cv; cv.b = h; return cv.u;
}
static __device__ __forceinline__ float b2f(unsigned short u) {
    union { float f; unsigned v; } c; c.v = ((unsigned)u) << 16; return c.f;
}

// ------ prep: bf16 conversions + W transposes -------------------------------
__global__ __launch_bounds__(256) void prep(
    const float* __restrict__ x_cls, const float* __restrict__ x_reg,
    const float* __restrict__ W_cls, const float* __restrict__ W_reg,
    unsigned short* __restrict__ xb_c, unsigned short* __restrict__ xb_r,
    unsigned short* __restrict__ Wt_c, unsigned short* __restrict__ Wt_r)
{
    const int u = blockIdx.x * 256 + threadIdx.x;   // 700416 total
    if (u < 393216) {
        xb_c[u] = f2b(x_cls[u]);
    } else if (u < 491520) {
        const int v = u - 393216;
        xb_r[v] = f2b(x_reg[v]);
    } else if (u < 688128) {
        const int v = u - 491520;                   // Wt_c[j*256+k] = W_cls[k*768+j]
        const int j = v >> 8, k = v & 255;
        Wt_c[v] = f2b(W_cls[k * 768 + j]);
    } else if (u < 700416) {
        const int v = u - 688128;                   // Wt_r[j*64+k] = W_reg[k*192+j]
        const int j = v >> 6, k = v & 63;
        Wt_r[v] = f2b(W_reg[k * 192 + j]);
    }
}

// ------ MFMA projection GEMM + fused per-head L2 normalize (2-deep prefetch) -
__global__ __launch_bounds__(256, 4) void gemm_mfma(
    const unsigned short* __restrict__ xb_c, const unsigned short* __restrict__ Wt_c,
    const unsigned short* __restrict__ xb_r, const unsigned short* __restrict__ Wt_r,
    float* __restrict__ qkv_c, unsigned short* __restrict__ qb_c,
    float* __restrict__ qkv_r, unsigned short* __restrict__ qb_r)
{
    const unsigned short *A, *B;
    float* qkv; unsigned short* qb;
    int K, NN, KS;
    const bool isreg = (blockIdx.z == 1);
    if (!isreg) { A = xb_c; B = Wt_c; qkv = qkv_c; qb = qb_c; K = 256; NN = 768; KS = 8; }
    else { if (blockIdx.x >= 3) return;
           A = xb_r; B = Wt_r; qkv = qkv_r; qb = qb_r; K = 64;  NN = 192; KS = 2; }
    __shared__ short Ai[64 * 40], Bj[64 * 40];
    const int t = threadIdx.x, lane = t & 63;
    const int wv = t >> 6, wr = wv >> 1, wc = wv & 1;
    const int i0 = blockIdx.y * 64, j0 = blockIdx.x * 64;
    const int srow = t >> 2, sc8 = (t & 3) * 8;
    f32x4 acc[2][2];
    #pragma unroll
    for (int a = 0; a < 2; a++)
        #pragma unroll
        for (int b = 0; b < 2; b++) acc[a][b] = (f32x4){0, 0, 0, 0};
    float4 ra = *(const float4*)&A[(i0 + srow) * K + 0 * 32 + sc8];
    float4 rb = *(const float4*)&B[(j0 + srow) * K + 0 * 32 + sc8];
    float4 ra2, rb2;
    if (KS > 1) {
        ra2 = *(const float4*)&A[(i0 + srow) * K + 1 * 32 + sc8];
        rb2 = *(const float4*)&B[(j0 + srow) * K + 1 * 32 + sc8];
    }
    for (int ks = 0; ks < KS; ks++) {
        __syncthreads();
        *(float4*)&Ai[srow * 40 + sc8] = ra;
        *(float4*)&Bj[srow * 40 + sc8] = rb;
        ra = ra2; rb = rb2;
        if (ks + 2 < KS) {
            ra2 = *(const float4*)&A[(i0 + srow) * K + (ks + 2) * 32 + sc8];
            rb2 = *(const float4*)&B[(j0 + srow) * K + (ks + 2) * 32 + sc8];
        }
        __syncthreads();
        const int k8 = (lane >> 4) * 8;
        bf16x8 af[2], bf_[2];
        #pragma unroll
        for (int fr = 0; fr < 2; fr++)
            af[fr] = *(const bf16x8*)&Ai[(wr * 32 + fr * 16 + (lane & 15)) * 40 + k8];
        #pragma unroll
        for (int fc = 0; fc < 2; fc++)
            bf_[fc] = *(const bf16x8*)&Bj[(wc * 32 + fc * 16 + (lane & 15)) * 40 + k8];
        #pragma unroll
        for (int fr = 0; fr < 2; fr++)
            #pragma unroll
            for (int fc = 0; fc < 2; fc++)
                acc[fr][fc] = __builtin_amdgcn_mfma_f32_16x16x32_bf16(af[fr], bf_[fc], acc[fr][fc], 0, 0, 0);
    }
    #pragma unroll
    for (int fr = 0; fr < 2; fr++)
        #pragma unroll
        for (int r4 = 0; r4 < 4; r4++) {
            const int i = i0 + wr * 32 + fr * 16 + (lane >> 4) * 4 + r4;
            if (!isreg) {
                float s = acc[fr][0][r4] * acc[fr][0][r4] + acc[fr][1][r4] * acc[fr][1][r4];
                s += __shfl_xor(s, 1); s += __shfl_xor(s, 2);
                s += __shfl_xor(s, 4); s += __shfl_xor(s, 8);
                const float inv = 1.0f / sqrtf(s);
                #pragma unroll
                for (int fc = 0; fc < 2; fc++) {
                    const int j = j0 + wc * 32 + fc * 16 + (lane & 15);
                    const float v = acc[fr][fc][r4];
                    qkv[i * NN + j] = v;
                    qb[i * NN + j] = f2b(v * inv);
                }
            } else {
                #pragma unroll
                for (int fc = 0; fc < 2; fc++) {
                    const float v = acc[fr][fc][r4];
                    float s = v * v;
                    s += __shfl_xor(s, 1); s += __shfl_xor(s, 2); s += __shfl_xor(s, 4);
                    const float inv = 1.0f / sqrtf(s);
                    const int j = j0 + wc * 32 + fc * 16 + (lane & 15);
                    qkv[i * NN + j] = v;
                    qb[i * NN + j] = f2b(v * inv);
                }
            }
        }
}

// ------ bits (blocks 0..575) ∥ denominators (blocks 576..1151) --------------
// __launch_bounds__(256,3): cap VGPR at 170 -> 3 blocks/CU (was 172 -> 2).
__global__ __launch_bounds__(256, 3) void bitsdenom(
    const unsigned short* __restrict__ qb_cls, const unsigned short* __restrict__ qb_reg,
    const float* __restrict__ cls_score, const float* __restrict__ fg_score,
    unsigned* __restrict__ simbits, unsigned* __restrict__ objbits,
    float* __restrict__ Dcpart, float* __restrict__ Drpart)
{
    __shared__ short Ai[64 * 40], Bj[64 * 40];
    __shared__ short Kr[64 * 72], Qr[64 * 72];
    __shared__ float csi[64], csj[64], fgi[64], fgj[64];
    __shared__ unsigned simw[64][2], objw[64][2];
    const int t = threadIdx.x;
    const int lane = t & 63;
    const int wv = t >> 6, wr = wv >> 1, wc = wv & 1;
    const int sr = t >> 2, sc = t & 3;

    if (blockIdx.x < 576) {
        // ================= bits branch (2-deep prefetch) =================
        const int iB = blockIdx.x / 24, jB = blockIdx.x % 24;
        const int i0 = iB * 64, j0 = jB * 64;
        if (t < 64)       { csi[t] = cls_score[i0 + t]; fgi[t] = fg_score[i0 + t]; }
        else if (t < 128) { csj[t - 64] = cls_score[j0 + t - 64]; fgj[t - 64] = fg_score[j0 + t - 64]; }
        f32x4 ac[2][2], ar[2][2];
        #pragma unroll
        for (int a = 0; a < 2; a++)
            #pragma unroll
            for (int b = 0; b < 2; b++) { ac[a][b] = (f32x4){0,0,0,0}; ar[a][b] = (f32x4){0,0,0,0}; }
        #define LD_A(s) ((s) < 8 ? *(const float4*)&qb_cls[(i0 + sr) * 768 + 512 + (s) * 32 + sc * 8] \
                                 : *(const float4*)&qb_reg[(i0 + sr) * 192 + 128 + ((s) - 8) * 32 + sc * 8])
        #define LD_B(s) ((s) < 8 ? *(const float4*)&qb_cls[(j0 + sr) * 768 + 512 + (s) * 32 + sc * 8] \
                                 : *(const float4*)&qb_reg[(j0 + sr) * 192 + 128 + ((s) - 8) * 32 + sc * 8])
        float4 ra = LD_A(0), rb = LD_B(0);
        float4 ra2 = LD_A(1), rb2 = LD_B(1);
        for (int ks = 0; ks < 10; ks++) {
            __syncthreads();
            *(float4*)&Ai[sr * 40 + sc * 8] = ra;
            *(float4*)&Bj[sr * 40 + sc * 8] = rb;
            ra = ra2; rb = rb2;
            if (ks + 2 < 10) { ra2 = LD_A(ks + 2); rb2 = LD_B(ks + 2); }
            __syncthreads();
            const int k8 = (lane >> 4) * 8;
            bf16x8 af[2], bf_[2];
            #pragma unroll
            for (int fr = 0; fr < 2; fr++)
                af[fr] = *(const bf16x8*)&Ai[(wr * 32 + fr * 16 + (lane & 15)) * 40 + k8];
            #pragma unroll
            for (int fc = 0; fc < 2; fc++)
                bf_[fc] = *(const bf16x8*)&Bj[(wc * 32 + fc * 16 + (lane & 15)) * 40 + k8];
            if (ks < 8) {
                #pragma unroll
                for (int fr = 0; fr < 2; fr++)
                    #pragma unroll
                    for (int fc = 0; fc < 2; fc++)
                        ac[fr][fc] = __builtin_amdgcn_mfma_f32_16x16x32_bf16(af[fr], bf_[fc], ac[fr][fc], 0, 0, 0);
            } else {
                #pragma unroll
                for (int fr = 0; fr < 2; fr++)
                    #pragma unroll
                    for (int fc = 0; fc < 2; fc++)
                        ar[fr][fc] = __builtin_amdgcn_mfma_f32_16x16x32_bf16(af[fr], bf_[fc], ar[fr][fc], 0, 0, 0);
            }
        }
        #undef LD_A
        #undef LD_B
        #pragma unroll
        for (int fr = 0; fr < 2; fr++)
            #pragma unroll
            for (int r4 = 0; r4 < 4; r4++) {
                const int rloc = wr * 32 + fr * 16 + (lane >> 4) * 4 + r4;
                const float ci = csi[rloc] - 0.1f, fgv = fgi[rloc] - 0.1f;
                unsigned sm[2], om[2];
                #pragma unroll
                for (int fc = 0; fc < 2; fc++) {
                    const int cloc = wc * 32 + fc * 16 + (lane & 15);
                    const bool clsb = csj[cloc] > ci;
                    const bool fgb  = fgj[cloc] > fgv;
                    const bool sim = (ac[fr][fc][r4] * 0.125f > 0.75f) && clsb && fgb;
                    const bool obj = sim && (ar[fr][fc][r4] * 0.125f > 0.75f);
                    unsigned long long bs = __ballot(sim);
                    unsigned long long bo = __ballot(obj);
                    const int g = lane >> 4;
                    sm[fc] = (unsigned)((bs >> (16 * g)) & 0xFFFFull);
                    om[fc] = (unsigned)((bo >> (16 * g)) & 0xFFFFull);
                }
                if ((lane & 15) == 0) {
                    simw[rloc][wc] = sm[0] | (sm[1] << 16);
                    objw[rloc][wc] = om[0] | (om[1] << 16);
                }
            }
        __syncthreads();
        if (t < 128) {
            const int row = t >> 1, w = t & 1;
            simbits[(i0 + row) * 48 + jB * 2 + w] = simw[row][w];
            objbits[(i0 + row) * 48 + jB * 2 + w] = objw[row][w];
        }
    } else {
        // ================= denominator branch (2-deep prefetch) =================
        const int vd = blockIdx.x - 576;
        const int iB = vd / 24, jB = vd % 24;
        const int i0 = iB * 64, j0 = jB * 64;
        if (t < 64)       csj[t] = cls_score[j0 + t];
        else if (t < 128) csi[t - 64] = cls_score[i0 + t - 64];
        #pragma unroll
        for (int it = 0; it < 2; it++) {
            const int u = it * 256 + t;
            const int r = u >> 3, c = u & 7;
            *(float4*)&Kr[r * 72 + c * 8] = *(const float4*)&qb_reg[(j0 + r) * 192 + 64 + c * 8];
            *(float4*)&Qr[r * 72 + c * 8] = *(const float4*)&qb_reg[(i0 + r) * 192 + 0 + c * 8];
        }
        __syncthreads();
        float cI[2], cJ[8];
        #pragma unroll
        for (int fc = 0; fc < 2; fc++) cI[fc] = csi[wc * 32 + fc * 16 + (lane & 15)] - 0.1f;
        #pragma unroll
        for (int fr = 0; fr < 2; fr++)
            #pragma unroll
            for (int r4 = 0; r4 < 4; r4++)
                cJ[fr * 4 + r4] = csj[wr * 32 + fr * 16 + (lane >> 4) * 4 + r4];
        const bool g0 = (lane >> 4) == 0;
        const bf16x8 zz = {0, 0, 0, 0, 0, 0, 0, 0};
        float4 ra = *(const float4*)&qb_cls[(j0 + sr) * 768 + 256 + 0 * 32 + sc * 8];
        float4 rb = *(const float4*)&qb_cls[(i0 + sr) * 768 + 0   + 0 * 32 + sc * 8];
        float4 ra2 = *(const float4*)&qb_cls[(j0 + sr) * 768 + 256 + 1 * 32 + sc * 8];
        float4 rb2 = *(const float4*)&qb_cls[(i0 + sr) * 768 + 0   + 1 * 32 + sc * 8];
        for (int h = 0; h < 8; h++) {
            __syncthreads();
            *(float4*)&Ai[sr * 40 + sc * 8] = ra;
            *(float4*)&Bj[sr * 40 + sc * 8] = rb;
            ra = ra2; rb = rb2;
            if (h + 2 < 8) {
                ra2 = *(const float4*)&qb_cls[(j0 + sr) * 768 + 256 + (h + 2) * 32 + sc * 8];
                rb2 = *(const float4*)&qb_cls[(i0 + sr) * 768 + 0   + (h + 2) * 32 + sc * 8];
            }
            __syncthreads();
            const int k8 = (lane >> 4) * 8;
            bf16x8 a[2], b[2], arg[2], brg[2];
            #pragma unroll
            for (int fr = 0; fr < 2; fr++) {
                const int row = wr * 32 + fr * 16 + (lane & 15);
                a[fr] = *(const bf16x8*)&Ai[row * 40 + k8];
                arg[fr] = g0 ? *(const bf16x8*)&Kr[row * 72 + h * 8] : zz;
            }
            #pragma unroll
            for (int fc = 0; fc < 2; fc++) {
                const int row = wc * 32 + fc * 16 + (lane & 15);
                b[fc] = *(const bf16x8*)&Bj[row * 40 + k8];
                brg[fc] = g0 ? *(const bf16x8*)&Qr[row * 72 + h * 8] : zz;
            }
            f32x4 acc[2][2], racc[2][2];
            #pragma unroll
            for (int fr = 0; fr < 2; fr++)
                #pragma unroll
                for (int fc = 0; fc < 2; fc++) {
                    acc[fr][fc] = (f32x4){0,0,0,0};
                    racc[fr][fc] = (f32x4){0,0,0,0};
                    acc[fr][fc] = __builtin_amdgcn_mfma_f32_16x16x32_bf16(a[fr], b[fc], acc[fr][fc], 0, 0, 0);
                    racc[fr][fc] = __builtin_amdgcn_mfma_f32_16x16x32_bf16(arg[fr], brg[fc], racc[fr][fc], 0, 0, 0);
                }
            // per-h reduce + store (replaces pC/pR[2][8] arrays: -32 VGPR,
            // identical values and summation order)
            #pragma unroll
            for (int fc = 0; fc < 2; fc++) {
                float sC = 0.f, sR = 0.f;
                #pragma unroll
                for (int fr = 0; fr < 2; fr++)
                    #pragma unroll
                    for (int r4 = 0; r4 < 4; r4++) {
                        const float cj = cJ[fr * 4 + r4];
                        const float lc = (cj > cI[fc]) ? acc[fr][fc][r4] * SCALE * cj : 0.0f;
                        sC += __expf(lc);
                        sR += __expf(racc[fr][fc][r4] * SCALE);
                    }
                float v = sC; v += __shfl_xor(v, 16); v += __shfl_xor(v, 32);
                float u = sR; u += __shfl_xor(u, 16); u += __shfl_xor(u, 32);
                if (lane < 16) {
                    const int i = i0 + wc * 32 + fc * 16 + lane;
                    const int p = jB * 2 + wr;
                    Dcpart[(p * NT + i) * 8 + h] = v;
                    Drpart[(p * NT + i) * 8 + h] = u;
                }
            }
        }
    }
}

// ------ finish: out rows (blocks 0..383) + mask expansion (384..4479) -------
__global__ __launch_bounds__(256, 4) void finish(
    const float* __restrict__ qkv_cls, const unsigned short* __restrict__ qb_cls,
    const float* __restrict__ qkv_reg, const unsigned short* __restrict__ qb_reg,
    const float* __restrict__ cls_score,
    const unsigned* __restrict__ simbits, const unsigned* __restrict__ objbits,
    const float* __restrict__ Dcpart, const float* __restrict__ Drpart,
    const float* __restrict__ x_cls, const float* __restrict__ x_reg,
    float* __restrict__ out_cls, float* __restrict__ out_reg,
    float* __restrict__ sim_out, float* __restrict__ obj_out)
{
    __shared__ unsigned bw[6][48];
    __shared__ float invs[6];
    const int t = threadIdx.x;
    if (blockIdx.x < 384) {
        // ---- sparse attn-out: one wave per row ----
        const int i = (blockIdx.x << 2) + (t >> 6);
        const int l = t & 63;
        const int g = l >> 3;
        const ushort4 qu = *(const ushort4*)&qb_cls[i * 768 + 4 * l];
        const float qx = b2f(qu.x), qy = b2f(qu.y), qz = b2f(qu.z), qw = b2f(qu.w);
        const float qr = b2f(qb_reg[i * 192 + l]);
        unsigned myw = (l < 48) ? objbits[i * 48 + l] : 0u;
        int cnt = __popc(myw);
        #pragma unroll
        for (int m = 1; m < 64; m <<= 1) cnt += __shfl_xor(cnt, m);
        const int s = l & 7;
        float Dcv = 0.f, Drv = 0.f;
        #pragma unroll
        for (int p6 = 0; p6 < 6; p6++) {
            const int p = s * 6 + p6;
            Dcv += Dcpart[(p * NT + i) * 8 + g];
            Drv += Drpart[(p * NT + i) * 8 + g];
        }
        Dcv += __shfl_xor(Dcv, 1); Dcv += __shfl_xor(Dcv, 2); Dcv += __shfl_xor(Dcv, 4);
        Drv += __shfl_xor(Drv, 1); Drv += __shfl_xor(Drv, 2); Drv += __shfl_xor(Drv, 4);
        float a1x = 0.f, a1y = 0.f, a1z = 0.f, a1w = 0.f;
        float a2x = 0.f, a2y = 0.f, a2z = 0.f, a2w = 0.f;
        float rr1 = 0.f, rr2 = 0.f;
        for (int w = 0; w < 48; w++) {
            unsigned bits = __shfl(myw, w);
            while (bits) {
                const int b = __ffs(bits) - 1;
                bits &= bits - 1u;
                const int j = w * 32 + b;
                const ushort4 ku = *(const ushort4*)&qb_cls[j * 768 + 256 + 4 * l];
                const float4 v4 = *(const float4*)&qkv_cls[j * 768 + 512 + 4 * l];
                const float kr = b2f(qb_reg[j * 192 + 64 + l]);
                const float vr = qkv_reg[j * 192 + 128 + l];
                float dc = qx * b2f(ku.x) + qy * b2f(ku.y) + qz * b2f(ku.z) + qw * b2f(ku.w);
                dc += __shfl_xor(dc, 1); dc += __shfl_xor(dc, 2); dc += __shfl_xor(dc, 4);
                float dr = qr * kr;
                dr += __shfl_xor(dr, 1); dr += __shfl_xor(dr, 2); dr += __shfl_xor(dr, 4);
                const float cj = cls_score[j];
                const float ec = __expf(dc * SCALE * cj);   // obj => cls_mask==1
                const float er = __expf(dr * SCALE);
                a1x += ec * v4.x; a1y += ec * v4.y; a1z += ec * v4.z; a1w += ec * v4.w;
                a2x += er * v4.x; a2y += er * v4.y; a2z += er * v4.z; a2w += er * v4.w;
                rr1 += ec * vr;   rr2 += er * vr;
            }
        }
        const float iDc = 1.0f / Dcv, iDr = 1.0f / Drv;
        const float hi = 0.5f / (float)cnt;
        float4 o;
        o.x = (a1x * iDc + a2x * iDr) * hi;
        o.y = (a1y * iDc + a2y * iDr) * hi;
        o.z = (a1z * iDc + a2z * iDr) * hi;
        o.w = (a1w * iDc + a2w * iDr) * hi;
        *(float4*)&out_cls[i * 512 + 4 * l] = o;
        out_reg[i * 128 + l] = (rr1 * iDc + rr2 * iDr) * hi;
        *(float4*)&out_cls[i * 512 + 256 + 4 * l] = *(const float4*)&x_cls[i * 256 + 4 * l];
        out_reg[i * 128 + 64 + l] = x_reg[i * 64 + l];
    } else {
        // ---- mask expansion: 6 contiguous rows of one head-copy, NT stores ----
        const int eb = blockIdx.x - 384;        // 0..4095
        const int arr = eb >> 11;               // 0: sim, 1: obj
        const int rem = eb & 2047;
        const int copy = rem >> 8;              // 0..7
        const int blk = rem & 255;
        const int r0 = blk * 6;
        const unsigned* src = arr ? objbits : simbits;
        for (int u = t; u < 288; u += 256) bw[u / 48][u % 48] = src[(r0 + u / 48) * 48 + (u % 48)];
        __syncthreads();
        if (t < 6) {
            int c = 0;
            #pragma unroll 8
            for (int w = 0; w < 48; w++) c += __popc(bw[t][w]);
            invs[t] = 1.0f / (float)c;
        }
        __syncthreads();
        f32x4* dst = (f32x4*)((arr ? obj_out : sim_out)
                              + (size_t)copy * NT * NT + (size_t)r0 * NT);
        #pragma unroll
        for (int rpt = 0; rpt < 9; rpt++) {
            const int u = rpt * 256 + t;        // 0..2303; dst[u] is linear
            const int row = u / 384;
            const int c4 = u - row * 384;
            const int j0 = c4 * 4;
            const unsigned w = bw[row][j0 >> 5] >> (j0 & 31);
            const float on = arr ? invs[row] : 1.0f;
            f32x4 v;
            v.x = (w & 1u) ? on : 0.f;
            v.y = (w & 2u) ? on : 0.f;
            v.z = (w & 4u) ? on : 0.f;
            v.w = (w & 8u) ? on : 0.f;
            __builtin_nontemporal_store(v, dst + u);
        }
    }
}

extern "C" void kernel_launch(void* const* d_in, const int* in_sizes, int n_in,
                              void* d_out, int out_size, void* d_ws, size_t ws_size,
                              hipStream_t stream)
{
    (void)in_sizes; (void)n_in; (void)out_size; (void)ws_size;
    const float* x_cls     = (const float*)d_in[0];
    const float* x_reg     = (const float*)d_in[1];
    const float* cls_score = (const float*)d_in[2];
    const float* fg_score  = (const float*)d_in[3];
    const float* W_cls     = (const float*)d_in[4];
    const float* W_reg     = (const float*)d_in[5];

    float* out = (float*)d_out;
    float* out_cls = out;                  // 786432 floats
    float* out_reg = out + 786432;         // 196608 floats
    float* sim_out = out + 983040;         // 18874368 floats
    float* obj_out = out + 19857408;       // 18874368 floats

    // Scratch in d_ws (~15.6 MB)
    float* wsf = (float*)d_ws;
    float* qkv_cls = wsf;                               // 1,179,648 f
    float* qkv_reg = wsf + 1179648;                     //   294,912 f
    float* Dcpart  = wsf + 1474560;                     //   589,824 f
    float* Drpart  = wsf + 2064384;                     //   589,824 f
    unsigned short* qb_cls = (unsigned short*)(wsf + 2654208);  // 1,179,648 u16
    unsigned short* qb_reg = (unsigned short*)(wsf + 3244032);  //   294,912 u16
    unsigned short* xb_c   = (unsigned short*)(wsf + 3391488);  //   393,216 u16
    unsigned short* xb_r   = (unsigned short*)(wsf + 3588096);  //    98,304 u16
    unsigned short* Wt_c   = (unsigned short*)(wsf + 3637248);  //   196,608 u16
    unsigned short* Wt_r   = (unsigned short*)(wsf + 3735552);  //    12,288 u16
    unsigned* simbits = (unsigned*)(wsf + 3741696);     //    73,728 u32
    unsigned* objbits = simbits + 73728;                //    73,728 u32

    prep<<<2736, 256, 0, stream>>>(x_cls, x_reg, W_cls, W_reg, xb_c, xb_r, Wt_c, Wt_r);
    gemm_mfma<<<dim3(12, 24, 2), 256, 0, stream>>>(
        xb_c, Wt_c, xb_r, Wt_r, qkv_cls, qb_cls, qkv_reg, qb_reg);
    bitsdenom<<<1152, 256, 0, stream>>>(
        qb_cls, qb_reg, cls_score, fg_score, simbits, objbits, Dcpart, Drpart);
    finish<<<4480, 256, 0, stream>>>(
        qkv_cls, qb_cls, qkv_reg, qb_reg, cls_score,
        simbits, objbits, Dcpart, Drpart, x_cls, x_reg,
        out_cls, out_reg, sim_out, obj_out);
}